// Round 22
// baseline (54.722 us; speedup 1.0000x reference)
//
#include <hip/hip_runtime.h>
#include <hip/hip_bf16.h>

// MultiHeadAttention: N=4, S=1024, D=512, H=8, dh=64. f32 in/out, bf16 compute.
// Pipeline: [prep f32->bf16] -> [qkv_gemm z=3] -> [attn] -> [out_gemm]
// Base = r21 (53.95us: r16 GEMMs + 1-wave attn blocks).
// r22: GEMM triple-buffered LDS (72KB), ONE barrier per K-step:
//   vmcnt(6) -> s_barrier -> COMPUTE(t, B[t%3]) -> STAGE(t+2, B[(t+2)%3]).
//   Race-safe: STAGE(t+2) overwrites B[(t-1)%3], last read in COMPUTE(t-1),
//   and every wave passed this iter's barrier after finishing COMPUTE(t-1).
//   Visibility: per-wave vmcnt BEFORE the barrier drains own tile-t loads.
//   Cost: 3->2 blocks/CU; gain: barrier count halves + 2-deep prefetch.
// ws (bf16): Xqb|Xkb|Xvb[2.1M ea] Wqb|Wkb|Wvb|Wob[262K ea] Qb|Kb|Vt|AO[2.1M ea]
// Qb pre-scaled by 1/sqrt(dh)=0.125.
// attn: r21 exactly (64-thr blocks, depth-3 rotation, defer-max, mask skip).

typedef short bf16x8 __attribute__((ext_vector_type(8)));
typedef float f32x4 __attribute__((ext_vector_type(4)));
typedef int   i32x4 __attribute__((ext_vector_type(4)));
typedef unsigned short u16;
typedef unsigned int   u32;

#define MFMA_BF16(A, B, C) __builtin_amdgcn_mfma_f32_16x16x32_bf16((A), (B), (C), 0, 0, 0)

typedef const __attribute__((address_space(1))) void gv_t;
typedef __attribute__((address_space(3))) void lv_t;

__device__ __forceinline__ u16 cvt_bf16(float f) {
    return __builtin_bit_cast(u16, __float2bfloat16(f));  // RNE
}
__device__ __forceinline__ u32 cvt2(float lo, float hi) {
    return (u32)cvt_bf16(lo) | ((u32)cvt_bf16(hi) << 16);
}

// ---- prep: convert 7 f32 tensors to bf16 (z = tensor id) ----
__global__ __launch_bounds__(256) void prep_kernel(
    const float* __restrict__ xq, const float* __restrict__ xk, const float* __restrict__ xv,
    const float* __restrict__ wq, const float* __restrict__ wk, const float* __restrict__ wv,
    const float* __restrict__ wo,
    u16* __restrict__ xqb, u16* __restrict__ xkb, u16* __restrict__ xvb,
    u16* __restrict__ wqb, u16* __restrict__ wkb, u16* __restrict__ wvb,
    u16* __restrict__ wob) {
    const int z = blockIdx.y;
    const float* src;
    u16* dst;
    int nblk;
    switch (z) {
        case 0: src = xq; dst = xqb; nblk = 1024; break;
        case 1: src = xk; dst = xkb; nblk = 1024; break;
        case 2: src = xv; dst = xvb; nblk = 1024; break;
        case 3: src = wq; dst = wqb; nblk = 128; break;
        case 4: src = wk; dst = wkb; nblk = 128; break;
        case 5: src = wv; dst = wvb; nblk = 128; break;
        default: src = wo; dst = wob; nblk = 128; break;
    }
    if (blockIdx.x >= (unsigned)nblk) return;
    size_t i = ((size_t)blockIdx.x * 256 + threadIdx.x) * 8;
    f32x4 a = *reinterpret_cast<const f32x4*>(src + i);
    f32x4 b = *reinterpret_cast<const f32x4*>(src + i + 4);
    i32x4 p;
    p[0] = cvt2(a[0], a[1]); p[1] = cvt2(a[2], a[3]);
    p[2] = cvt2(b[0], b[1]); p[3] = cvt2(b[2], b[3]);
    *reinterpret_cast<i32x4*>(dst + i) = p;
}

// ---- GEMM: C = (X @ W^T + bias) * scale, X/W bf16 row-major K-inner ----
// BM=128, BN=64. OMODE: 0 = f32 out, 1 = bf16 out, 2 = bf16 Vt[mh][d][s].
// Triple-buffer / one-barrier schedule (see header).
template <int OMODE>
__device__ __forceinline__ void gemm_bf(const u16* __restrict__ X,
                                        const u16* __restrict__ W,
                                        const float* __restrict__ bias,
                                        void* __restrict__ out_, float scale) {
    extern __shared__ char smem[];  // 3 x (As 16KB | Bs 8KB) = 72KB

    const int tid = threadIdx.x;
    const int m0 = blockIdx.x * 128;
    const int n0 = blockIdx.y * 64;
    const int w = tid >> 6, l = tid & 63;
    const int wm = (w >> 1) * 64, wn = (w & 1) * 32;
    const int lg = l >> 4, lr = l & 15;

    const int row8 = l >> 3;
    const int slotg = (l & 7) ^ row8;
    const u16* gA = X + (size_t)(m0 + w * 32 + row8) * 512 + slotg * 8;
    const u16* gB = W + (size_t)(n0 + w * 16 + row8) * 512 + slotg * 8;

    f32x4 acc[4][2];
#pragma unroll
    for (int i = 0; i < 4; i++)
#pragma unroll
        for (int j = 0; j < 2; j++) acc[i][j] = (f32x4){0.f, 0.f, 0.f, 0.f};

    auto STAGE = [&](int t, int buf) {  // 6 global_load_lds per lane
        char* As = smem + buf * 24576;
        char* Bs = As + 16384;
        const int k0 = t * 64;
#pragma unroll
        for (int c = 0; c < 4; c++)
            __builtin_amdgcn_global_load_lds((gv_t*)(gA + (size_t)c * 8 * 512 + k0),
                                             (lv_t*)(As + (w * 4 + c) * 1024), 16, 0, 0);
#pragma unroll
        for (int c = 0; c < 2; c++)
            __builtin_amdgcn_global_load_lds((gv_t*)(gB + (size_t)c * 8 * 512 + k0),
                                             (lv_t*)(Bs + (w * 2 + c) * 1024), 16, 0, 0);
    };
    auto COMPUTE = [&](int buf) {
        char* As = smem + buf * 24576;
        char* Bs = As + 16384;
#pragma unroll
        for (int kk = 0; kk < 2; kk++) {
            bf16x8 af[4], bfr[2];
#pragma unroll
            for (int i = 0; i < 4; i++) {
                int ra_ = wm + i * 16 + lr;
                af[i] = *reinterpret_cast<const bf16x8*>(
                    As + ra_ * 128 + ((kk * 64 + lg * 16) ^ ((ra_ & 7) << 4)));
            }
#pragma unroll
            for (int j = 0; j < 2; j++) {
                int rb_ = wn + j * 16 + lr;
                bfr[j] = *reinterpret_cast<const bf16x8*>(
                    Bs + rb_ * 128 + ((kk * 64 + lg * 16) ^ ((rb_ & 7) << 4)));
            }
            __builtin_amdgcn_s_setprio(1);
#pragma unroll
            for (int i = 0; i < 4; i++)
#pragma unroll
                for (int j = 0; j < 2; j++) acc[i][j] = MFMA_BF16(af[i], bfr[j], acc[i][j]);
            __builtin_amdgcn_s_setprio(0);
        }
    };

    STAGE(0, 0);
    STAGE(1, 1);
#pragma unroll
    for (int t = 0; t < 8; ++t) {
        if (t < 7) {
            asm volatile("s_waitcnt vmcnt(6)" ::: "memory");  // tile t landed
        } else {
            asm volatile("s_waitcnt vmcnt(0)" ::: "memory");
        }
        __builtin_amdgcn_s_barrier();       // all waves' tile-t writes visible;
                                            // also: COMPUTE(t-1) done everywhere
        __builtin_amdgcn_sched_barrier(0);  // keep ds_reads below the barrier
        COMPUTE(t % 3);
        if (t < 6) STAGE(t + 2, (t + 2) % 3);  // overwrites B[(t-1)%3]: safe
    }

#pragma unroll
    for (int j = 0; j < 2; j++) {
        int col = n0 + wn + j * 16 + lr;
        float bc_ = bias[col];
#pragma unroll
        for (int i = 0; i < 4; i++) {
            int grbase = m0 + wm + i * 16 + lg * 4;
            if (OMODE == 0) {
                float* out = (float*)out_;
#pragma unroll
                for (int r = 0; r < 4; r++)
                    out[(size_t)(grbase + r) * 512 + col] = (acc[i][j][r] + bc_) * scale;
            } else if (OMODE == 1) {
                u16* out = (u16*)out_;
#pragma unroll
                for (int r = 0; r < 4; r++)
                    out[(size_t)(grbase + r) * 512 + col] = cvt_bf16((acc[i][j][r] + bc_) * scale);
            } else {
                u16* out = (u16*)out_;
                int mh = ((grbase >> 10) * 8) + (col >> 6);
                int t2 = grbase & 1023;
                u32 p0 = cvt2((acc[i][j][0] + bc_) * scale, (acc[i][j][1] + bc_) * scale);
                u32 p1 = cvt2((acc[i][j][2] + bc_) * scale, (acc[i][j][3] + bc_) * scale);
                u32* dst = reinterpret_cast<u32*>(out + ((size_t)mh * 64 + (col & 63)) * 1024 + t2);
                dst[0] = p0;
                dst[1] = p1;
            }
        }
    }
}

__global__ __launch_bounds__(256) void qkv_gemm(
    const u16* __restrict__ Xq, const u16* __restrict__ Xk, const u16* __restrict__ Xv,
    const u16* __restrict__ Wq, const u16* __restrict__ Wk, const u16* __restrict__ Wv,
    const float* __restrict__ bq, const float* __restrict__ bk, const float* __restrict__ bv,
    u16* __restrict__ Qb, u16* __restrict__ Kb, u16* __restrict__ Vt) {
    int z = blockIdx.z;
    if (z == 0)      gemm_bf<1>(Xq, Wq, bq, Qb, 0.125f);  // Q pre-scaled
    else if (z == 1) gemm_bf<1>(Xk, Wk, bk, Kb, 1.0f);
    else             gemm_bf<2>(Xv, Wv, bv, Vt, 1.0f);
}

__global__ __launch_bounds__(256) void out_gemm(const u16* __restrict__ AO,
                                                const u16* __restrict__ Wo,
                                                const float* __restrict__ bo,
                                                float* __restrict__ out) {
    gemm_bf<0>(AO, Wo, bo, out, 1.0f);
}

// ---- Flash attention (r21): ONE WAVE per block (64 thr), grid 2048 ----
// Fine-grained blocks let the CU scheduler balance variable-nt (prefix) work.
// s-tiles of 32; swapped QK^T (S^T = K x Q); depth-3 K/V register rotation.
// Mask: attend iff s < prefix[n] || s == q. Q carries the 0.125 scale.
__global__ __launch_bounds__(64) void attn_kernel(const u16* __restrict__ Qb,
                                                  const u16* __restrict__ Kb,
                                                  const u16* __restrict__ Vt,
                                                  const int* __restrict__ prefix,
                                                  u16* __restrict__ AO) {
    const int l = threadIdx.x;
    const int lg = l >> 4, lr = l & 15;
    const int qblk = blockIdx.x;  // 0..63 (16 q-rows each)
    const int m = blockIdx.y;     // 0..31 (n*8+h)
    const int n = m >> 3, h = m & 7;
    const int q0 = qblk * 16;
    const int P = prefix[n];

    const u16* qptr = Qb + (size_t)(n * 1024 + q0 + lr) * 512 + h * 64 + lg * 8;
    bf16x8 qf0 = *reinterpret_cast<const bf16x8*>(qptr);
    bf16x8 qf1 = *reinterpret_cast<const bf16x8*>(qptr + 32);

    f32x4 o[4];
#pragma unroll
    for (int j = 0; j < 4; j++) o[j] = (f32x4){0.f, 0.f, 0.f, 0.f};
    float mrow = -1.0e9f, lsum = 0.f;

    const int T = (P + 31) >> 5;
    const int dt = q0 >> 5;
    const int nt = T + ((dt >= T) ? 1 : 0);
    const int q_glob = q0 + lr;
    const f32x4 fz = (f32x4){0.f, 0.f, 0.f, 0.f};

    const u16* kbase = Kb + (size_t)(n * 1024 + lr) * 512 + h * 64 + lg * 8;
    const u16* vbase = Vt + ((size_t)m * 64 + lr) * 1024 + lg * 8;

    struct KV { bf16x8 k0, k1, k2, k3, v0, v1, v2, v3; };

    auto s0_of = [&](int it) { return ((it < T) ? it : dt) << 5; };
    auto LOADKV = [&](int s0, KV& t) {
        const u16* kp = kbase + (size_t)s0 * 512;
        t.k0 = *reinterpret_cast<const bf16x8*>(kp);
        t.k1 = *reinterpret_cast<const bf16x8*>(kp + 32);
        t.k2 = *reinterpret_cast<const bf16x8*>(kp + 16 * 512);
        t.k3 = *reinterpret_cast<const bf16x8*>(kp + 16 * 512 + 32);
        const u16* vp = vbase + s0;
        t.v0 = *reinterpret_cast<const bf16x8*>(vp);
        t.v1 = *reinterpret_cast<const bf16x8*>(vp + 16 * 1024);
        t.v2 = *reinterpret_cast<const bf16x8*>(vp + 32 * 1024);
        t.v3 = *reinterpret_cast<const bf16x8*>(vp + 48 * 1024);
    };
    auto STEP = [&](int s0, const KV& t) {
        f32x4 st[2];
        __builtin_amdgcn_s_setprio(1);
        st[0] = MFMA_BF16(t.k0, qf0, fz);
        st[0] = MFMA_BF16(t.k1, qf1, st[0]);
        st[1] = MFMA_BF16(t.k2, qf0, fz);
        st[1] = MFMA_BF16(t.k3, qf1, st[1]);
        __builtin_amdgcn_s_setprio(0);

        // Mask only when the tile intersects the masked region (wave-uniform).
        if (s0 + 32 > P) {
#pragma unroll
            for (int c = 0; c < 2; c++)
#pragma unroll
                for (int r = 0; r < 4; r++) {
                    int s = s0 + c * 16 + lg * 4 + r;
                    if (!((s < P) || (s == q_glob))) st[c][r] = -1.0e9f;
                }
        }

        // Row stats (per q = lr; lane-local 8, then xor 16/32).
        float tm = st[0][0];
#pragma unroll
        for (int r = 1; r < 4; r++) tm = fmaxf(tm, st[0][r]);
#pragma unroll
        for (int r = 0; r < 4; r++) tm = fmaxf(tm, st[1][r]);
        tm = fmaxf(tm, __shfl_xor(tm, 16));
        tm = fmaxf(tm, __shfl_xor(tm, 32));

        // T13 defer-max: keep old max while growth <= 8 (wave-uniform).
        const bool defer = __all(tm - mrow <= 8.0f);
        const float Mn = defer ? mrow : fmaxf(mrow, tm);

        float ts = 0.f;
#pragma unroll
        for (int c = 0; c < 2; c++)
#pragma unroll
            for (int r = 0; r < 4; r++) {
                float p = __expf(st[c][r] - Mn);
                st[c][r] = p;
                ts += p;
            }
        ts += __shfl_xor(ts, 16);
        ts += __shfl_xor(ts, 32);

        if (defer) {
            lsum += ts;
        } else {
            float alpha = __expf(mrow - Mn);
            lsum = lsum * alpha + ts;
            mrow = Mn;
            float a4[4];
#pragma unroll
            for (int r = 0; r < 4; r++) a4[r] = __shfl(alpha, lg * 4 + r);
#pragma unroll
            for (int j = 0; j < 4; j++) {
                o[j][0] *= a4[0]; o[j][1] *= a4[1]; o[j][2] *= a4[2]; o[j][3] *= a4[3];
            }
        }

        // P^T -> PV A-frag via packed bf16 pairs + shfl gather.
        u32 pk[2][2];
#pragma unroll
        for (int c = 0; c < 2; c++) {
            pk[c][0] = cvt2(st[c][0], st[c][1]);
            pk[c][1] = cvt2(st[c][2], st[c][3]);
        }
        i32x4 pav;
#pragma unroll
        for (int wd = 0; wd < 4; wd++) {
            int src = ((2 * (lg & 1) + (wd >> 1)) << 4) + lr;
            int t0 = __shfl((int)pk[0][wd & 1], src);
            int t1 = __shfl((int)pk[1][wd & 1], src);
            pav[wd] = (lg >> 1) ? t1 : t0;
        }
        bf16x8 paf = __builtin_bit_cast(bf16x8, pav);

        __builtin_amdgcn_s_setprio(1);
        o[0] = MFMA_BF16(paf, t.v0, o[0]);
        o[1] = MFMA_BF16(paf, t.v1, o[1]);
        o[2] = MFMA_BF16(paf, t.v2, o[2]);
        o[3] = MFMA_BF16(paf, t.v3, o[3]);
        __builtin_amdgcn_s_setprio(0);
    };

    // Depth-3 rotation: two tiles always in flight (named buffers, rule #20).
    KV A_, B_, C_;
    LOADKV(s0_of(0), A_);
    if (1 < nt) LOADKV(s0_of(1), B_);
    for (int it = 0; it < nt; it += 3) {
        if (it + 2 < nt) LOADKV(s0_of(it + 2), C_);
        STEP(s0_of(it), A_);
        if (it + 1 >= nt) break;
        if (it + 3 < nt) LOADKV(s0_of(it + 3), A_);
        STEP(s0_of(it + 1), B_);
        if (it + 2 >= nt) break;
        if (it + 4 < nt) LOADKV(s0_of(it + 4), B_);
        STEP(s0_of(it + 2), C_);
    }

    float linv = 1.0f / fmaxf(lsum, 1.0e-30f);
    float li[4];
#pragma unroll
    for (int r = 0; r < 4; r++) li[r] = __shfl(linv, lg * 4 + r);

    u16* obase = AO + (size_t)(n * 1024 + q0 + lg * 4) * 512 + h * 64 + lr;
#pragma unroll
    for (int j = 0; j < 4; j++)
#pragma unroll
        for (int r = 0; r < 4; r++) {
            float v = fminf(fmaxf(o[j][r] * li[r], -1.0e4f), 1.0e4f);
            obase[(size_t)r * 512 + j * 16] = cvt_bf16(v);
        }
}

extern "C" void kernel_launch(void* const* d_in, const int* in_sizes, int n_in,
                              void* d_out, int out_size, void* d_ws, size_t ws_size,
                              hipStream_t stream) {
    (void)in_sizes; (void)n_in; (void)out_size;
    const float* queries = (const float*)d_in[0];
    const float* keys    = (const float*)d_in[1];
    const float* values  = (const float*)d_in[2];
    const int*   prefix  = (const int*)d_in[3];
    const float* Wq = (const float*)d_in[4];
    const float* bq = (const float*)d_in[5];
    const float* Wk = (const float*)d_in[6];
    const float* bk = (const float*)d_in[7];
    const float* Wv = (const float*)d_in[8];
    const float* bv = (const float*)d_in[9];
    const float* Wo = (const float*)d_in[10];
    const float* bo = (const float*)d_in[11];
    float* outp = (float*)d_out;

    const size_t XEL = (size_t)4096 * 512;  // 2.097M
    const size_t WEL = (size_t)512 * 512;   // 262K
    size_t need = (7 * XEL + 4 * WEL) * sizeof(u16);
    if (ws_size < need) return;
    u16* Xqb = (u16*)d_ws;
    u16* Xkb = Xqb + XEL;
    u16* Xvb = Xkb + XEL;
    u16* Wqb = Xvb + XEL;
    u16* Wkb = Wqb + WEL;
    u16* Wvb = Wkb + WEL;
    u16* Wob = Wvb + WEL;
    u16* Qb  = Wob + WEL;
    u16* Kb  = Qb + XEL;
    u16* Vt  = Kb + XEL;
    u16* AO  = Vt + XEL;

    dim3 blk(256);
    prep_kernel<<<dim3(1024, 7), blk, 0, stream>>>(queries, keys, values, Wq, Wk, Wv, Wo,
                                                   Xqb, Xkb, Xvb, Wqb, Wkb, Wvb, Wob);
    const int SMEM = 73728;  // 3 x (16KB As + 8KB Bs)
    qkv_gemm<<<dim3(32, 8, 3), blk, SMEM, stream>>>(Xqb, Xkb, Xvb, Wqb, Wkb, Wvb,
                                                    bq, bk, bv, Qb, Kb, Vt);
    attn_kernel<<<dim3(64, 32), dim3(64), 0, stream>>>(Qb, Kb, Vt, prefix, AO);
    out_gemm<<<dim3(32, 8, 1), blk, SMEM, stream>>>(AO, Wob, bo, outp);
}

// Round 23
// 53.865 us; speedup vs baseline: 1.0159x; 1.0159x over previous
//
#include <hip/hip_runtime.h>
#include <hip/hip_bf16.h>

// MultiHeadAttention: N=4, S=1024, D=512, H=8, dh=64. f32 in/out, bf16 compute.
// Pipeline: [prep f32->bf16] -> [qkv_gemm z=3] -> [attn] -> [out_gemm]
// FINAL-LINE CONFIG = r21 (53.95us), reverting r22's tribuf experiment:
//  - GEMM: 128x64 tile, BK=64, DUAL-buffer 48KB LDS (3 blocks/CU),
//    counted-vmcnt schedule (T4): STAGE(t+1) -> vmcnt(6) -> s_barrier ->
//    COMPUTE(t) -> s_barrier; prefetch stays in flight across both barriers.
//    (r22 tribuf/1-barrier = 54.7: occupancy loss beat barrier savings.)
//  - attn: 1-wave blocks (64 thr), grid 2048 -> prefix-imbalance backfill
//    (r21: -3.8us); depth-3 K/V reg rotation; T13 defer-max; mask skip.
//  - prep: bf16 pre-conversion of X,W (r12 inline-f32 variant regressed).
// History: r9 fused-persistent REVERTED (cross-XCD fences); r10 64-key attn
// REVERTED (VGPR); r13 remapped grids REVERTED; r14 8-wave attn REVERTED.
// ws (bf16): Xqb|Xkb|Xvb[2.1M ea] Wqb|Wkb|Wvb|Wob[262K ea] Qb|Kb|Vt|AO[2.1M ea]
// Qb pre-scaled by 1/sqrt(dh)=0.125.

typedef short bf16x8 __attribute__((ext_vector_type(8)));
typedef float f32x4 __attribute__((ext_vector_type(4)));
typedef int   i32x4 __attribute__((ext_vector_type(4)));
typedef unsigned short u16;
typedef unsigned int   u32;

#define MFMA_BF16(A, B, C) __builtin_amdgcn_mfma_f32_16x16x32_bf16((A), (B), (C), 0, 0, 0)

typedef const __attribute__((address_space(1))) void gv_t;
typedef __attribute__((address_space(3))) void lv_t;

__device__ __forceinline__ u16 cvt_bf16(float f) {
    return __builtin_bit_cast(u16, __float2bfloat16(f));  // RNE
}
__device__ __forceinline__ u32 cvt2(float lo, float hi) {
    return (u32)cvt_bf16(lo) | ((u32)cvt_bf16(hi) << 16);
}

// ---- prep: convert 7 f32 tensors to bf16 (z = tensor id) ----
__global__ __launch_bounds__(256) void prep_kernel(
    const float* __restrict__ xq, const float* __restrict__ xk, const float* __restrict__ xv,
    const float* __restrict__ wq, const float* __restrict__ wk, const float* __restrict__ wv,
    const float* __restrict__ wo,
    u16* __restrict__ xqb, u16* __restrict__ xkb, u16* __restrict__ xvb,
    u16* __restrict__ wqb, u16* __restrict__ wkb, u16* __restrict__ wvb,
    u16* __restrict__ wob) {
    const int z = blockIdx.y;
    const float* src;
    u16* dst;
    int nblk;
    switch (z) {
        case 0: src = xq; dst = xqb; nblk = 1024; break;
        case 1: src = xk; dst = xkb; nblk = 1024; break;
        case 2: src = xv; dst = xvb; nblk = 1024; break;
        case 3: src = wq; dst = wqb; nblk = 128; break;
        case 4: src = wk; dst = wkb; nblk = 128; break;
        case 5: src = wv; dst = wvb; nblk = 128; break;
        default: src = wo; dst = wob; nblk = 128; break;
    }
    if (blockIdx.x >= (unsigned)nblk) return;
    size_t i = ((size_t)blockIdx.x * 256 + threadIdx.x) * 8;
    f32x4 a = *reinterpret_cast<const f32x4*>(src + i);
    f32x4 b = *reinterpret_cast<const f32x4*>(src + i + 4);
    i32x4 p;
    p[0] = cvt2(a[0], a[1]); p[1] = cvt2(a[2], a[3]);
    p[2] = cvt2(b[0], b[1]); p[3] = cvt2(b[2], b[3]);
    *reinterpret_cast<i32x4*>(dst + i) = p;
}

// ---- GEMM: C = (X @ W^T + bias) * scale, X/W bf16 row-major K-inner ----
// BM=128, BN=64. OMODE: 0 = f32 out, 1 = bf16 out, 2 = bf16 Vt[mh][d][s].
// Counted-vmcnt schedule (T4): STAGE(t+1) -> vmcnt(6) -> barrier -> COMPUTE(t)
// -> barrier; the prefetch stays in flight across both barriers.
template <int OMODE>
__device__ __forceinline__ void gemm_bf(const u16* __restrict__ X,
                                        const u16* __restrict__ W,
                                        const float* __restrict__ bias,
                                        void* __restrict__ out_, float scale) {
    extern __shared__ char smem[];  // [2][As 16KB | Bs 8KB]

    const int tid = threadIdx.x;
    const int m0 = blockIdx.x * 128;
    const int n0 = blockIdx.y * 64;
    const int w = tid >> 6, l = tid & 63;
    const int wm = (w >> 1) * 64, wn = (w & 1) * 32;
    const int lg = l >> 4, lr = l & 15;

    const int row8 = l >> 3;
    const int slotg = (l & 7) ^ row8;
    const u16* gA = X + (size_t)(m0 + w * 32 + row8) * 512 + slotg * 8;
    const u16* gB = W + (size_t)(n0 + w * 16 + row8) * 512 + slotg * 8;

    f32x4 acc[4][2];
#pragma unroll
    for (int i = 0; i < 4; i++)
#pragma unroll
        for (int j = 0; j < 2; j++) acc[i][j] = (f32x4){0.f, 0.f, 0.f, 0.f};

    auto STAGE = [&](int t, int buf) {  // 6 global_load_lds per lane
        char* As = smem + buf * 24576;
        char* Bs = As + 16384;
        const int k0 = t * 64;
#pragma unroll
        for (int c = 0; c < 4; c++)
            __builtin_amdgcn_global_load_lds((gv_t*)(gA + (size_t)c * 8 * 512 + k0),
                                             (lv_t*)(As + (w * 4 + c) * 1024), 16, 0, 0);
#pragma unroll
        for (int c = 0; c < 2; c++)
            __builtin_amdgcn_global_load_lds((gv_t*)(gB + (size_t)c * 8 * 512 + k0),
                                             (lv_t*)(Bs + (w * 2 + c) * 1024), 16, 0, 0);
    };
    auto COMPUTE = [&](int buf) {
        char* As = smem + buf * 24576;
        char* Bs = As + 16384;
#pragma unroll
        for (int kk = 0; kk < 2; kk++) {
            bf16x8 af[4], bfr[2];
#pragma unroll
            for (int i = 0; i < 4; i++) {
                int ra_ = wm + i * 16 + lr;
                af[i] = *reinterpret_cast<const bf16x8*>(
                    As + ra_ * 128 + ((kk * 64 + lg * 16) ^ ((ra_ & 7) << 4)));
            }
#pragma unroll
            for (int j = 0; j < 2; j++) {
                int rb_ = wn + j * 16 + lr;
                bfr[j] = *reinterpret_cast<const bf16x8*>(
                    Bs + rb_ * 128 + ((kk * 64 + lg * 16) ^ ((rb_ & 7) << 4)));
            }
            __builtin_amdgcn_s_setprio(1);
#pragma unroll
            for (int i = 0; i < 4; i++)
#pragma unroll
                for (int j = 0; j < 2; j++) acc[i][j] = MFMA_BF16(af[i], bfr[j], acc[i][j]);
            __builtin_amdgcn_s_setprio(0);
        }
    };

    STAGE(0, 0);
    int buf = 0;
#pragma unroll
    for (int t = 0; t < 8; ++t) {
        if (t < 7) {
            STAGE(t + 1, buf ^ 1);  // stays in flight across BOTH barriers
            asm volatile("s_waitcnt vmcnt(6)" ::: "memory");  // tile t landed
        } else {
            asm volatile("s_waitcnt vmcnt(0)" ::: "memory");
        }
        __builtin_amdgcn_s_barrier();       // all waves' tile-t LDS writes visible
        __builtin_amdgcn_sched_barrier(0);  // keep ds_reads below the barrier
        COMPUTE(buf);
        __builtin_amdgcn_s_barrier();       // readers done before buf is re-staged
        buf ^= 1;
    }

#pragma unroll
    for (int j = 0; j < 2; j++) {
        int col = n0 + wn + j * 16 + lr;
        float bc_ = bias[col];
#pragma unroll
        for (int i = 0; i < 4; i++) {
            int grbase = m0 + wm + i * 16 + lg * 4;
            if (OMODE == 0) {
                float* out = (float*)out_;
#pragma unroll
                for (int r = 0; r < 4; r++)
                    out[(size_t)(grbase + r) * 512 + col] = (acc[i][j][r] + bc_) * scale;
            } else if (OMODE == 1) {
                u16* out = (u16*)out_;
#pragma unroll
                for (int r = 0; r < 4; r++)
                    out[(size_t)(grbase + r) * 512 + col] = cvt_bf16((acc[i][j][r] + bc_) * scale);
            } else {
                u16* out = (u16*)out_;
                int mh = ((grbase >> 10) * 8) + (col >> 6);
                int t2 = grbase & 1023;
                u32 p0 = cvt2((acc[i][j][0] + bc_) * scale, (acc[i][j][1] + bc_) * scale);
                u32 p1 = cvt2((acc[i][j][2] + bc_) * scale, (acc[i][j][3] + bc_) * scale);
                u32* dst = reinterpret_cast<u32*>(out + ((size_t)mh * 64 + (col & 63)) * 1024 + t2);
                dst[0] = p0;
                dst[1] = p1;
            }
        }
    }
}

__global__ __launch_bounds__(256) void qkv_gemm(
    const u16* __restrict__ Xq, const u16* __restrict__ Xk, const u16* __restrict__ Xv,
    const u16* __restrict__ Wq, const u16* __restrict__ Wk, const u16* __restrict__ Wv,
    const float* __restrict__ bq, const float* __restrict__ bk, const float* __restrict__ bv,
    u16* __restrict__ Qb, u16* __restrict__ Kb, u16* __restrict__ Vt) {
    int z = blockIdx.z;
    if (z == 0)      gemm_bf<1>(Xq, Wq, bq, Qb, 0.125f);  // Q pre-scaled
    else if (z == 1) gemm_bf<1>(Xk, Wk, bk, Kb, 1.0f);
    else             gemm_bf<2>(Xv, Wv, bv, Vt, 1.0f);
}

__global__ __launch_bounds__(256) void out_gemm(const u16* __restrict__ AO,
                                                const u16* __restrict__ Wo,
                                                const float* __restrict__ bo,
                                                float* __restrict__ out) {
    gemm_bf<0>(AO, Wo, bo, out, 1.0f);
}

// ---- Flash attention: ONE WAVE per block (64 thr), 16 q-rows; grid 2048 ----
// Fine-grained blocks let the CU scheduler balance variable-nt (prefix) work.
// s-tiles of 32; swapped QK^T (S^T = K x Q); depth-3 K/V register rotation.
// Mask: attend iff s < prefix[n] || s == q. Q carries the 0.125 scale.
__global__ __launch_bounds__(64) void attn_kernel(const u16* __restrict__ Qb,
                                                  const u16* __restrict__ Kb,
                                                  const u16* __restrict__ Vt,
                                                  const int* __restrict__ prefix,
                                                  u16* __restrict__ AO) {
    const int l = threadIdx.x;
    const int lg = l >> 4, lr = l & 15;
    const int qblk = blockIdx.x;  // 0..63 (16 q-rows each)
    const int m = blockIdx.y;     // 0..31 (n*8+h)
    const int n = m >> 3, h = m & 7;
    const int q0 = qblk * 16;
    const int P = prefix[n];

    const u16* qptr = Qb + (size_t)(n * 1024 + q0 + lr) * 512 + h * 64 + lg * 8;
    bf16x8 qf0 = *reinterpret_cast<const bf16x8*>(qptr);
    bf16x8 qf1 = *reinterpret_cast<const bf16x8*>(qptr + 32);

    f32x4 o[4];
#pragma unroll
    for (int j = 0; j < 4; j++) o[j] = (f32x4){0.f, 0.f, 0.f, 0.f};
    float mrow = -1.0e9f, lsum = 0.f;

    const int T = (P + 31) >> 5;
    const int dt = q0 >> 5;
    const int nt = T + ((dt >= T) ? 1 : 0);
    const int q_glob = q0 + lr;
    const f32x4 fz = (f32x4){0.f, 0.f, 0.f, 0.f};

    const u16* kbase = Kb + (size_t)(n * 1024 + lr) * 512 + h * 64 + lg * 8;
    const u16* vbase = Vt + ((size_t)m * 64 + lr) * 1024 + lg * 8;

    struct KV { bf16x8 k0, k1, k2, k3, v0, v1, v2, v3; };

    auto s0_of = [&](int it) { return ((it < T) ? it : dt) << 5; };
    auto LOADKV = [&](int s0, KV& t) {
        const u16* kp = kbase + (size_t)s0 * 512;
        t.k0 = *reinterpret_cast<const bf16x8*>(kp);
        t.k1 = *reinterpret_cast<const bf16x8*>(kp + 32);
        t.k2 = *reinterpret_cast<const bf16x8*>(kp + 16 * 512);
        t.k3 = *reinterpret_cast<const bf16x8*>(kp + 16 * 512 + 32);
        const u16* vp = vbase + s0;
        t.v0 = *reinterpret_cast<const bf16x8*>(vp);
        t.v1 = *reinterpret_cast<const bf16x8*>(vp + 16 * 1024);
        t.v2 = *reinterpret_cast<const bf16x8*>(vp + 32 * 1024);
        t.v3 = *reinterpret_cast<const bf16x8*>(vp + 48 * 1024);
    };
    auto STEP = [&](int s0, const KV& t) {
        f32x4 st[2];
        __builtin_amdgcn_s_setprio(1);
        st[0] = MFMA_BF16(t.k0, qf0, fz);
        st[0] = MFMA_BF16(t.k1, qf1, st[0]);
        st[1] = MFMA_BF16(t.k2, qf0, fz);
        st[1] = MFMA_BF16(t.k3, qf1, st[1]);
        __builtin_amdgcn_s_setprio(0);

        // Mask only when the tile intersects the masked region (wave-uniform).
        if (s0 + 32 > P) {
#pragma unroll
            for (int c = 0; c < 2; c++)
#pragma unroll
                for (int r = 0; r < 4; r++) {
                    int s = s0 + c * 16 + lg * 4 + r;
                    if (!((s < P) || (s == q_glob))) st[c][r] = -1.0e9f;
                }
        }

        // Row stats (per q = lr; lane-local 8, then xor 16/32).
        float tm = st[0][0];
#pragma unroll
        for (int r = 1; r < 4; r++) tm = fmaxf(tm, st[0][r]);
#pragma unroll
        for (int r = 0; r < 4; r++) tm = fmaxf(tm, st[1][r]);
        tm = fmaxf(tm, __shfl_xor(tm, 16));
        tm = fmaxf(tm, __shfl_xor(tm, 32));

        // T13 defer-max: keep old max while growth <= 8 (wave-uniform).
        const bool defer = __all(tm - mrow <= 8.0f);
        const float Mn = defer ? mrow : fmaxf(mrow, tm);

        float ts = 0.f;
#pragma unroll
        for (int c = 0; c < 2; c++)
#pragma unroll
            for (int r = 0; r < 4; r++) {
                float p = __expf(st[c][r] - Mn);
                st[c][r] = p;
                ts += p;
            }
        ts += __shfl_xor(ts, 16);
        ts += __shfl_xor(ts, 32);

        if (defer) {
            lsum += ts;
        } else {
            float alpha = __expf(mrow - Mn);
            lsum = lsum * alpha + ts;
            mrow = Mn;
            float a4[4];
#pragma unroll
            for (int r = 0; r < 4; r++) a4[r] = __shfl(alpha, lg * 4 + r);
#pragma unroll
            for (int j = 0; j < 4; j++) {
                o[j][0] *= a4[0]; o[j][1] *= a4[1]; o[j][2] *= a4[2]; o[j][3] *= a4[3];
            }
        }

        // P^T -> PV A-frag via packed bf16 pairs + shfl gather.
        u32 pk[2][2];
#pragma unroll
        for (int c = 0; c < 2; c++) {
            pk[c][0] = cvt2(st[c][0], st[c][1]);
            pk[c][1] = cvt2(st[c][2], st[c][3]);
        }
        i32x4 pav;
#pragma unroll
        for (int wd = 0; wd < 4; wd++) {
            int src = ((2 * (lg & 1) + (wd >> 1)) << 4) + lr;
            int t0 = __shfl((int)pk[0][wd & 1], src);
            int t1 = __shfl((int)pk[1][wd & 1], src);
            pav[wd] = (lg >> 1) ? t1 : t0;
        }
        bf16x8 paf = __builtin_bit_cast(bf16x8, pav);

        __builtin_amdgcn_s_setprio(1);
        o[0] = MFMA_BF16(paf, t.v0, o[0]);
        o[1] = MFMA_BF16(paf, t.v1, o[1]);
        o[2] = MFMA_BF16(paf, t.v2, o[2]);
        o[3] = MFMA_BF16(paf, t.v3, o[3]);
        __builtin_amdgcn_s_setprio(0);
    };

    // Depth-3 rotation: two tiles always in flight (named buffers, rule #20).
    KV A_, B_, C_;
    LOADKV(s0_of(0), A_);
    if (1 < nt) LOADKV(s0_of(1), B_);
    for (int it = 0; it < nt; it += 3) {
        if (it + 2 < nt) LOADKV(s0_of(it + 2), C_);
        STEP(s0_of(it), A_);
        if (it + 1 >= nt) break;
        if (it + 3 < nt) LOADKV(s0_of(it + 3), A_);
        STEP(s0_of(it + 1), B_);
        if (it + 2 >= nt) break;
        if (it + 4 < nt) LOADKV(s0_of(it + 4), B_);
        STEP(s0_of(it + 2), C_);
    }

    float linv = 1.0f / fmaxf(lsum, 1.0e-30f);
    float li[4];
#pragma unroll
    for (int r = 0; r < 4; r++) li[r] = __shfl(linv, lg * 4 + r);

    u16* obase = AO + (size_t)(n * 1024 + q0 + lg * 4) * 512 + h * 64 + lr;
#pragma unroll
    for (int j = 0; j < 4; j++)
#pragma unroll
        for (int r = 0; r < 4; r++) {
            float v = fminf(fmaxf(o[j][r] * li[r], -1.0e4f), 1.0e4f);
            obase[(size_t)r * 512 + j * 16] = cvt_bf16(v);
        }
}

extern "C" void kernel_launch(void* const* d_in, const int* in_sizes, int n_in,
                              void* d_out, int out_size, void* d_ws, size_t ws_size,
                              hipStream_t stream) {
    (void)in_sizes; (void)n_in; (void)out_size;
    const float* queries = (const float*)d_in[0];
    const float* keys    = (const float*)d_in[1];
    const float* values  = (const float*)d_in[2];
    const int*   prefix  = (const int*)d_in[3];
    const float* Wq = (const float*)d_in[4];
    const float* bq = (const float*)d_in[5];
    const float* Wk = (const float*)d_in[6];
    const float* bk = (const float*)d_in[7];
    const float* Wv = (const float*)d_in[8];
    const float* bv = (const float*)d_in[9];
    const float* Wo = (const float*)d_in[10];
    const float* bo = (const float*)d_in[11];
    float* outp = (float*)d_out;

    const size_t XEL = (size_t)4096 * 512;  // 2.097M
    const size_t WEL = (size_t)512 * 512;   // 262K
    size_t need = (7 * XEL + 4 * WEL) * sizeof(u16);
    if (ws_size < need) return;
    u16* Xqb = (u16*)d_ws;
    u16* Xkb = Xqb + XEL;
    u16* Xvb = Xkb + XEL;
    u16* Wqb = Xvb + XEL;
    u16* Wkb = Wqb + WEL;
    u16* Wvb = Wkb + WEL;
    u16* Wob = Wvb + WEL;
    u16* Qb  = Wob + WEL;
    u16* Kb  = Qb + XEL;
    u16* Vt  = Kb + XEL;
    u16* AO  = Vt + XEL;

    dim3 blk(256);
    prep_kernel<<<dim3(1024, 7), blk, 0, stream>>>(queries, keys, values, Wq, Wk, Wv, Wo,
                                                   Xqb, Xkb, Xvb, Wqb, Wkb, Wvb, Wob);
    const int SMEM = 49152;  // 2 x (16KB As + 8KB Bs)
    qkv_gemm<<<dim3(32, 8, 3), blk, SMEM, stream>>>(Xqb, Xkb, Xvb, Wqb, Wkb, Wvb,
                                                    bq, bk, bv, Qb, Kb, Vt);
    attn_kernel<<<dim3(64, 32), dim3(64), 0, stream>>>(Qb, Kb, Vt, prefix, AO);
    out_gemm<<<dim3(32, 8, 1), blk, SMEM, stream>>>(AO, Wob, bo, outp);
}